// Round 6
// baseline (2113.751 us; speedup 1.0000x reference)
//
#include <hip/hip_runtime.h>
#include <math.h>

// TransformersLSTM: T=512, I=512, H=1024, L=512, O=1.
// Split-grid persistent kernel: blocks 0..127 encoder, 128..255 decoder.
// Weights VGPR-resident. Tagless handoff: ws is 0xAA-poisoned pre-launch and
// slots are write-once, so consumers spin on data granules themselves
// (dword != 0xAAAAAAAA), per-thread, barrier-free.
// R6: publishers MULTICAST h into nrep disjoint replicas (scalar dword
// stores, wave-coalesced); consumer block b polls only replica b&(nrep-1).
// This cuts per-LLC-line poll concurrency ~8x — R5's 3.85us/step was the
// poll storm serializing at the line's bank (2048 pollers x ~1.5ns >> RTT).

#define T_STEPS 512
#define ENC_BLK 128
#define NBLK    256
#define SPIN_LIMIT 200000u
#define REP_STRIDE ((size_t)T_STEPS * 1024)

typedef float fv4 __attribute__((ext_vector_type(4)));

__device__ __forceinline__ float sigf(float x) { return 1.0f / (1.0f + expf(-x)); }

__device__ __forceinline__ unsigned ld_u(unsigned* p) {
  return __hip_atomic_load(p, __ATOMIC_RELAXED, __HIP_MEMORY_SCOPE_AGENT);
}
__device__ __forceinline__ void st_u(unsigned* p, unsigned v) {
  __hip_atomic_store(p, v, __ATOMIC_RELAXED, __HIP_MEMORY_SCOPE_AGENT);
}

// 16B cache-bypass load (L1+L2 bypass -> LLC), waits for completion.
__device__ __forceinline__ fv4 ld_bypass16(const float* p) {
  fv4 v;
  asm volatile("global_load_dwordx4 %0, %1, off sc0 sc1\n\t"
               "s_waitcnt vmcnt(0)"
               : "=&v"(v) : "v"(p) : "memory");
  return v;
}
// 4B cache-bypass store (write-through to LLC); wave-coalesced per line.
__device__ __forceinline__ void st_bypass4(float* p, float v) {
  asm volatile("global_store_dword %0, %1, off sc0 sc1"
               :: "v"(p), "v"(v) : "memory");
}

__device__ __forceinline__ bool valid4(fv4 v) {
  return __float_as_uint(v.x) != 0xAAAAAAAAu && __float_as_uint(v.y) != 0xAAAAAAAAu &&
         __float_as_uint(v.z) != 0xAAAAAAAAu && __float_as_uint(v.w) != 0xAAAAAAAAu;
}

// barrier-free per-thread poll on this thread's own 16B granule.
__device__ __forceinline__ fv4 poll_data(const float* p, unsigned* abortf, int* okp) {
  fv4 v;
  unsigned spins = 0;
  int ok = 1;
  for (;;) {
    v = ld_bypass16(p);
    if (valid4(v)) break;
    ++spins;
    if (spins > 4u) __builtin_amdgcn_s_sleep(1);  // backoff when genuinely early
    if ((spins & 63u) == 0u) {
      if (ld_u(abortf) != 0u || spins > SPIN_LIMIT) { ok = 0; break; }
    }
  }
  *okp = ok;
  return v;
}

// ------------- precompute PX = W_ih_e @ x_t + b_ih_e + b_hh_e -----------------
// px[(t*1024 + h)*4 + g] for gate row r = g*1024 + h. Also zeroes abortf.
__global__ __launch_bounds__(256) void prep_gemm(const float* __restrict__ X,
                                                 const float* __restrict__ Wih,
                                                 const float* __restrict__ bih,
                                                 const float* __restrict__ bhh,
                                                 float* __restrict__ px,
                                                 unsigned* abortf) {
  if (blockIdx.x == 0 && blockIdx.y == 0 && threadIdx.x == 0) st_u(abortf, 0u);
  __shared__ float Ws[64][68];
  __shared__ float Xs[64][68];
  const int r0 = blockIdx.x * 64;
  const int t0 = blockIdx.y * 64;
  const int tid = threadIdx.x;
  const int tr = tid & 15;
  const int tc = tid >> 4;
  float acc[4][4] = {{0.f}};
  for (int k0 = 0; k0 < 512; k0 += 64) {
    __syncthreads();
    const int lr = tid >> 4;
    const int lc = (tid & 15) * 4;
#pragma unroll
    for (int rep = 0; rep < 4; rep++) {
      const int row = lr + rep * 16;
      const float4 wv = *(const float4*)&Wih[(size_t)(r0 + row) * 512 + k0 + lc];
      Ws[lc + 0][row] = wv.x; Ws[lc + 1][row] = wv.y;
      Ws[lc + 2][row] = wv.z; Ws[lc + 3][row] = wv.w;
      const float4 xv = *(const float4*)&X[(size_t)(t0 + row) * 512 + k0 + lc];
      Xs[row][lc + 0] = xv.x; Xs[row][lc + 1] = xv.y;
      Xs[row][lc + 2] = xv.z; Xs[row][lc + 3] = xv.w;
    }
    __syncthreads();
    for (int kk = 0; kk < 64; kk++) {
      float a[4], x[4];
#pragma unroll
      for (int i = 0; i < 4; i++) a[i] = Ws[kk][tr * 4 + i];
#pragma unroll
      for (int j = 0; j < 4; j++) x[j] = Xs[tc * 4 + j][kk];
#pragma unroll
      for (int i = 0; i < 4; i++)
#pragma unroll
        for (int j = 0; j < 4; j++) acc[i][j] += a[i] * x[j];
    }
  }
#pragma unroll
  for (int i = 0; i < 4; i++) {
    const int r = r0 + tr * 4 + i;
    const int g = r >> 10, h = r & 1023;
    const float bsum = bih[r] + bhh[r];
#pragma unroll
    for (int j = 0; j < 4; j++) {
      const int t = t0 + tc * 4 + j;
      px[((size_t)t * 1024 + h) * 4 + g] = acc[i][j] + bsum;
    }
  }
}

// ------------------------------ persistent kernel -----------------------------
__global__ __launch_bounds__(256, 1) void lstm_persist(
    const float* __restrict__ Whhe, const float* __restrict__ Wattn,
    const float* __restrict__ battn, const float* __restrict__ Wihd,
    const float* __restrict__ Whhd, const float* __restrict__ bihd,
    const float* __restrict__ bhhd, const float* __restrict__ Wout,
    const float* __restrict__ bout, const float* __restrict__ px,
    float* ehbuf, float* dhbuf, int nrep, unsigned* abortf, float* out) {
  __shared__ float4 xbuf[256];   // eh broadcast copy
  __shared__ float4 dbuf[256];   // dh broadcast copy (decoder only)
  __shared__ float  aw[512];     // replicated softmax state (decoder only)
  __shared__ float  GA[32];      // gate exchange (enc ge / dec g1)
  __shared__ float  GB[32];      // dec g2
  __shared__ float  redE[4];     // energy (eh part) reduce
  __shared__ float  redE2[4];    // energy (dh part) reduce
  __shared__ float  red[8];      // softmax sum reduce
  __shared__ float  red2[4];     // out-dot reduce
  __shared__ float  bd[32];      // decoder bias slice
  __shared__ int    sbad;        // block failure flag (idempotent writes)

  const int b    = blockIdx.x;
  const int tid  = threadIdx.x;
  const int w    = tid >> 6;   // wave = gate (i,f,g,o)
  const int lane = tid & 63;
  const int jj   = lane & 7;   // h-lane within block (8 per block)
  const int seg  = lane >> 3;  // K-segment 0..7 (128 floats each)
  const size_t myrep = (size_t)(b & (nrep - 1)) * REP_STRIDE;

  if (b < ENC_BLK) {
    // =========================== encoder group ===============================
    const int e = b;
    const int r = (w << 10) + (e << 3) + jj;  // owned gate row
    float4 we[32];  // W_hh_e row slice, VGPR-resident, seg-rotation permuted
#pragma unroll
    for (int k = 0; k < 32; k++) {
      const int m = (k + seg) & 31;
      we[k] = *(const float4*)&Whhe[(size_t)r * 1024 + seg * 128 + m * 4];
    }
    xbuf[tid] = make_float4(0.f, 0.f, 0.f, 0.f);
    if (tid == 0) sbad = 0;
    float ec = 0.f;  // own cell state (lanes tid<8)
    __syncthreads();

    for (int t = 0; t < T_STEPS; t++) {
      float pxv = 0.f;
      if (seg == 0) pxv = px[((size_t)t * 1024 + (e << 3) + jj) * 4 + w];
      float ge = 0.f;
#pragma unroll
      for (int k = 0; k < 32; k++) {
        const int m = (k + seg) & 31;
        const float4 x = xbuf[seg * 32 + m];
        ge += we[k].x * x.x + we[k].y * x.y + we[k].z * x.z + we[k].w * x.w;
      }
      ge += __shfl_xor(ge, 8, 64);
      ge += __shfl_xor(ge, 16, 64);
      ge += __shfl_xor(ge, 32, 64);
      if (seg == 0) GA[(w << 3) + jj] = ge + pxv;
      __syncthreads();  // S1
      if (tid < 8) {
        const float gi = GA[tid], gf = GA[8 + tid], gg = GA[16 + tid], go = GA[24 + tid];
        const float c = sigf(gf) * ec + sigf(gi) * tanhf(gg);
        ec = c;
        const float h = sigf(go) * tanhf(c);
        // multicast publication: one scalar store per replica (wave-coalesced)
        for (int rp = 0; rp < nrep; rp++)
          st_bypass4(&ehbuf[(size_t)rp * REP_STRIDE + (size_t)t * 1024 + (e << 3) + tid], h);
      }
      // barrier-free per-thread poll of own eh(t) granule in own replica
      int ok;
      const fv4 ev = poll_data(&ehbuf[myrep + (size_t)t * 1024 + tid * 4], abortf, &ok);
      if (!ok) { st_u(abortf, 1u); sbad = 1; }
      xbuf[tid] = make_float4(ev.x, ev.y, ev.z, ev.w);
      __syncthreads();  // S2
      if (sbad) break;
    }
  } else {
    // =========================== decoder group ===============================
    const int d = b - ENC_BLK;
    const int r = (w << 10) + (d << 3) + jj;  // owned decoder gate row
    float4 w1[32], wr[32];  // Wihd[:, :H] and (Wihd[:,H:]+Whhd), permuted
#pragma unroll
    for (int k = 0; k < 32; k++) {
      const int m = (k + seg) & 31;
      w1[k] = *(const float4*)&Wihd[(size_t)r * 2048 + seg * 128 + m * 4];
      const float4 a = *(const float4*)&Wihd[(size_t)r * 2048 + 1024 + seg * 128 + m * 4];
      const float4 c = *(const float4*)&Whhd[(size_t)r * 1024 + seg * 128 + m * 4];
      wr[k] = make_float4(a.x + c.x, a.y + c.y, a.z + c.z, a.w + c.w);
    }
    if (tid < 32) {
      const int g = tid >> 3, j = tid & 7;
      bd[tid] = bihd[(g << 10) + (d << 3) + j] + bhhd[(g << 10) + (d << 3) + j];
    }
    xbuf[tid] = make_float4(0.f, 0.f, 0.f, 0.f);
    dbuf[tid] = make_float4(0.f, 0.f, 0.f, 0.f);
    aw[tid] = 0.f; aw[tid + 256] = 0.f;
    if (tid == 0) sbad = 0;
    float dc = 0.f;  // own cell state (lanes tid<8)
    const float4 wo = *(const float4*)&Wout[tid * 4];
    const float boutv = bout[0];
    __syncthreads();

    bool failed = false;
    for (int t = 0; t < T_STEPS; t++) {
      // --- pre-dh work: attention row, softmax partials over stale aw ---
      const float4 wae = *(const float4*)&Wattn[(size_t)t * 2048 + tid * 4];
      const float4 wad = *(const float4*)&Wattn[(size_t)t * 2048 + 1024 + tid * 4];
      const float battn_t = battn[t];
      const float ex0 = expf(aw[tid]);        // energies are O(1): no max needed
      const float ex1 = expf(aw[tid + 256]);
      float so = ((tid == t) ? 0.f : ex0) + ((tid + 256 == t) ? 0.f : ex1);
#pragma unroll
      for (int mk = 1; mk <= 32; mk <<= 1) so += __shfl_xor(so, mk, 64);
      if (lane == 0) red[w] = so;

      // --- poll eh(t) (encoder runs ahead; usually 1 iteration) ---
      int ok1;
      const fv4 ev = poll_data(&ehbuf[myrep + (size_t)t * 1024 + tid * 4], abortf, &ok1);
      if (!ok1) { st_u(abortf, 1u); sbad = 1; }
      float epe = wae.x * ev.x + wae.y * ev.y + wae.z * ev.z + wae.w * ev.w;
#pragma unroll
      for (int mk = 1; mk <= 32; mk <<= 1) epe += __shfl_xor(epe, mk, 64);
      if (lane == 0) redE[w] = epe;
      xbuf[tid] = make_float4(ev.x, ev.y, ev.z, ev.w);
      __syncthreads();  // S1
      if (sbad) { failed = true; break; }

      // --- g1 = Wihd[:,:H] @ eh(t) (dh-independent) ---
      float g1 = 0.f;
#pragma unroll
      for (int k = 0; k < 32; k++) {
        const int m = (k + seg) & 31;
        const float4 x = xbuf[seg * 32 + m];
        g1 += w1[k].x * x.x + w1[k].y * x.y + w1[k].z * x.z + w1[k].w * x.w;
      }
      g1 += __shfl_xor(g1, 8, 64); g1 += __shfl_xor(g1, 16, 64); g1 += __shfl_xor(g1, 32, 64);
      if (seg == 0) GA[(w << 3) + jj] = g1;

      // --- poll dh(t-1): the recurrence-critical handoff ---
      fv4 dv = {0.f, 0.f, 0.f, 0.f};
      float epd = 0.f;
      if (t > 0) {
        int ok2;
        dv = poll_data(&dhbuf[myrep + (size_t)(t - 1) * 1024 + tid * 4], abortf, &ok2);
        if (!ok2) { st_u(abortf, 1u); sbad = 1; }
        epd = wad.x * dv.x + wad.y * dv.y + wad.z * dv.z + wad.w * dv.w;
      }
#pragma unroll
      for (int mk = 1; mk <= 32; mk <<= 1) epd += __shfl_xor(epd, mk, 64);
      if (lane == 0) redE2[w] = epd;
      dbuf[tid] = make_float4(dv.x, dv.y, dv.z, dv.w);
      __syncthreads();  // S2
      if (sbad) { failed = true; break; }

      // --- g2 = (Wihd[:,H:]+Whhd) @ dh(t-1) ---
      float g2 = 0.f;
#pragma unroll
      for (int k = 0; k < 32; k++) {
        const int m = (k + seg) & 31;
        const float4 dd = dbuf[seg * 32 + m];
        g2 += wr[k].x * dd.x + wr[k].y * dd.y + wr[k].z * dd.z + wr[k].w * dd.w;
      }
      g2 += __shfl_xor(g2, 8, 64); g2 += __shfl_xor(g2, 16, 64); g2 += __shfl_xor(g2, 32, 64);
      if (seg == 0) GB[(w << 3) + jj] = g2;

      // --- scalar softmax finish + aw update ---
      const float sum_other = red[0] + red[1] + red[2] + red[3];
      const float e_t = redE[0] + redE[1] + redE[2] + redE[3] +
                        redE2[0] + redE2[1] + redE2[2] + redE2[3] + battn_t;
      const float exden = expf(e_t);
      const float inv = 1.f / (sum_other + exden);
      aw[tid] = ((tid == t) ? exden : ex0) * inv;
      aw[tid + 256] = ((tid + 256 == t) ? exden : ex1) * inv;
      const float awt = exden * inv;
      __syncthreads();  // S3 (GB + aw ready)

      // --- decoder cell + multicast dh publication ---
      if (tid < 8) {
        const float gi = awt * GA[tid]      + GB[tid]      + bd[tid];
        const float gf = awt * GA[8 + tid]  + GB[8 + tid]  + bd[8 + tid];
        const float gg = awt * GA[16 + tid] + GB[16 + tid] + bd[16 + tid];
        const float go = awt * GA[24 + tid] + GB[24 + tid] + bd[24 + tid];
        const float c = sigf(gf) * dc + sigf(gi) * tanhf(gg);
        dc = c;
        const float h = sigf(go) * tanhf(c);
        for (int rp = 0; rp < nrep; rp++)
          st_bypass4(&dhbuf[(size_t)rp * REP_STRIDE + (size_t)t * 1024 + (d << 3) + tid], h);
      }
    }

    // --- epilogue: out[t] = W_out·dh(t) + b_out, 4 t-values per block ---
    if (!failed) {
#pragma unroll
      for (int i = 0; i < 4; i++) {
        const int t = d * 4 + i;
        int ok;
        const fv4 dv = poll_data(&dhbuf[myrep + (size_t)t * 1024 + tid * 4], abortf, &ok);
        if (!ok) break;
        float op = wo.x * dv.x + wo.y * dv.y + wo.z * dv.z + wo.w * dv.w;
#pragma unroll
        for (int mk = 1; mk <= 32; mk <<= 1) op += __shfl_xor(op, mk, 64);
        if (lane == 0) red2[w] = op;
        __syncthreads();
        if (tid == 0) out[t] = red2[0] + red2[1] + red2[2] + red2[3] + boutv;
        __syncthreads();
      }
    }
  }
}

// ---------------------------------- launch ------------------------------------
extern "C" void kernel_launch(void* const* d_in, const int* in_sizes, int n_in,
                              void* d_out, int out_size, void* d_ws, size_t ws_size,
                              hipStream_t stream) {
  const float* X     = (const float*)d_in[0];
  const float* Wihe  = (const float*)d_in[2];
  const float* Whhe  = (const float*)d_in[3];
  const float* bihe  = (const float*)d_in[4];
  const float* bhhe  = (const float*)d_in[5];
  const float* Wattn = (const float*)d_in[6];
  const float* battn = (const float*)d_in[7];
  const float* Wihd  = (const float*)d_in[8];
  const float* Whhd  = (const float*)d_in[9];
  const float* bihd  = (const float*)d_in[10];
  const float* bhhd  = (const float*)d_in[11];
  const float* Wo    = (const float*)d_in[12];
  const float* bo    = (const float*)d_in[13];
  float* out = (float*)d_out;

  // pick largest replica count that fits the workspace
  const size_t px_elems = (size_t)T_STEPS * 1024 * 4;
  int nrep = 8;
  size_t need;
  for (;; nrep >>= 1) {
    need = (px_elems + 2 * (size_t)nrep * REP_STRIDE) * sizeof(float) + sizeof(unsigned);
    if (need <= ws_size || nrep == 1) break;
  }
  if (ws_size < need) return;

  float* ws    = (float*)d_ws;
  float* px    = ws;                                   // 8 MB
  float* ehbuf = px + px_elems;                        // nrep x 2 MB replicas
  float* dhbuf = ehbuf + (size_t)nrep * REP_STRIDE;    // nrep x 2 MB replicas
  unsigned* abortf = (unsigned*)(dhbuf + (size_t)nrep * REP_STRIDE);

  prep_gemm<<<dim3(64, 8), 256, 0, stream>>>(X, Wihe, bihe, bhhe, px, abortf);
  lstm_persist<<<NBLK, 256, 0, stream>>>(
      Whhe, Wattn, battn, Wihd, Whhd, bihd, bhhd, Wo, bo, px, ehbuf, dhbuf,
      nrep, abortf, out);
}